// Round 1
// baseline (1680.014 us; speedup 1.0000x reference)
//
#include <hip/hip_runtime.h>
#include <math.h>

#define N_NODES 100000
#define N_EDGES 1000000
#define IN_F 128
#define HID 64
#define OUT_F 64
#define NLAYERS 4
#define ALPHA 0.1f
#define BN_EPS 1e-5f

// ---- workspace layout (bytes), all 16B-aligned ----
// zero region: cnt (N ints) + stats (NLAYERS*128 floats)
static const size_t OFF_CNT      = 0;                       // N*4      = 400000
static const size_t OFF_STATS    = 400000;                  // 512*4    = 2048
static const size_t ZERO_BYTES   = 402048;
static const size_t OFF_DINV     = 402048;                  // N*4
static const size_t OFF_ROWSTART = 802048;                  // (N+1)*4 -> pad 400016
static const size_t OFF_CURSOR   = 1202064;                 // N*4
static const size_t OFF_SORTED   = 1602064;                 // E*4 = 4000000
static const size_t OFF_X0       = 5602064;                 // N*64*4 = 25600000
static const size_t OFF_BUF1     = 31202064;
static const size_t OFF_BUF2     = 56802064;                // end = 82402064

__global__ void hist_kernel(const int* __restrict__ row, int* __restrict__ cnt, int e) {
    int i = blockIdx.x * blockDim.x + threadIdx.x;
    if (i < e) atomicAdd(&cnt[row[i]], 1);
}

__global__ void dinv_kernel(const int* __restrict__ cnt, float* __restrict__ dinv, int n) {
    int i = blockIdx.x * blockDim.x + threadIdx.x;
    if (i < n) {
        int d = cnt[i];
        dinv[i] = d > 0 ? rsqrtf((float)d) : 0.0f;
    }
}

// single-block exclusive scan over n counts -> row_start[0..n], cursor copy
__global__ void scan_kernel(const int* __restrict__ cnt, int* __restrict__ rs,
                            int* __restrict__ cur, int n) {
    __shared__ int lds[1024];
    int t = threadIdx.x;
    int chunk = (n + 1023) >> 10;
    int b = t * chunk;
    int e = b + chunk; if (e > n) e = n;
    int s = 0;
    for (int j = b; j < e; ++j) s += cnt[j];
    lds[t] = s;
    __syncthreads();
    for (int off = 1; off < 1024; off <<= 1) {
        int v = lds[t];
        int add = (t >= off) ? lds[t - off] : 0;
        __syncthreads();
        lds[t] = v + add;
        __syncthreads();
    }
    int excl = (t == 0) ? 0 : lds[t - 1];
    for (int j = b; j < e; ++j) { rs[j] = excl; cur[j] = excl; excl += cnt[j]; }
    if (t == 1023) rs[n] = lds[1023];
}

__global__ void scatter_kernel(const int* __restrict__ edges, int* __restrict__ cur,
                               int* __restrict__ scol, int e) {
    int i = blockIdx.x * blockDim.x + threadIdx.x;
    if (i < e) {
        int r = edges[i];
        int c = edges[e + i];
        int pos = atomicAdd(&cur[r], 1);
        scol[pos] = c;
    }
}

// x0 = relu(x @ W0 + b0)  [N,128]@[128,64]; wave-per-row, W0 column in regs, shfl broadcast
__global__ __launch_bounds__(256) void fc0_kernel(const float* __restrict__ x,
        const float* __restrict__ W0, const float* __restrict__ b0,
        float* __restrict__ out, int n) {
    int wave = threadIdx.x >> 6, lane = threadIdx.x & 63;
    float w[IN_F];
#pragma unroll
    for (int k = 0; k < IN_F; ++k) w[k] = W0[k * HID + lane];
    float bias = b0[lane];
    for (int base = blockIdx.x * 4; base < n; base += gridDim.x * 4) {
        int r = base + wave;
        if (r >= n) continue;           // wave-uniform
        float xa = x[r * IN_F + lane];
        float xb = x[r * IN_F + 64 + lane];
        float acc0 = bias, acc1 = 0.f;
#pragma unroll
        for (int k = 0; k < 64; ++k) {
            acc0 += __shfl(xa, k, 64) * w[k];
            acc1 += __shfl(xb, k, 64) * w[64 + k];
        }
        float v = acc0 + acc1;
        out[r * HID + lane] = v > 0.f ? v : 0.f;
    }
}

// per layer: s = (1-a)*D^-1/2 A D^-1/2 x + a*x0 ; h = (1-beta)*s + beta*(s@cw);
// write h, accumulate per-channel sum/sumsq
__global__ __launch_bounds__(256) void layerA_kernel(const float* __restrict__ xcur,
        const float* __restrict__ x0, const float* __restrict__ dinv,
        const int* __restrict__ rs, const int* __restrict__ scol,
        const float* __restrict__ cw, float* __restrict__ h,
        float* __restrict__ stats, float beta, int n) {
    int wave = threadIdx.x >> 6, lane = threadIdx.x & 63;
    float w[HID];
#pragma unroll
    for (int k = 0; k < HID; ++k) w[k] = cw[k * HID + lane];
    float lsum = 0.f, lsq = 0.f;
    for (int base = blockIdx.x * 4; base < n; base += gridDim.x * 4) {
        int r = base + wave;
        if (r >= n) continue;           // wave-uniform
        int e0 = rs[r], e1 = rs[r + 1];
        float agg = 0.f;
        for (int e = e0; e < e1; ++e) {
            int c = scol[e];
            agg += dinv[c] * xcur[c * HID + lane];
        }
        float s = (1.f - ALPHA) * dinv[r] * agg + ALPHA * x0[r * HID + lane];
        float m = 0.f;
#pragma unroll
        for (int k = 0; k < HID; ++k) m += __shfl(s, k, 64) * w[k];
        float hv = (1.f - beta) * s + beta * m;
        h[r * HID + lane] = hv;
        lsum += hv; lsq += hv * hv;
    }
    atomicAdd(&stats[lane], lsum);
    atomicAdd(&stats[64 + lane], lsq);
}

// BN(train, biased var) + residual + relu, in place on h
__global__ void layerB_kernel(float* __restrict__ h, const float* __restrict__ xprev,
        const float* __restrict__ stats, const float* __restrict__ gamma,
        const float* __restrict__ bnb, int total) {
    int i = blockIdx.x * blockDim.x + threadIdx.x;
    if (i >= total) return;
    int f = i & 63;
    float mu = stats[f] * (1.0f / N_NODES);
    float var = stats[64 + f] * (1.0f / N_NODES) - mu * mu;
    if (var < 0.f) var = 0.f;
    float inv = rsqrtf(var + BN_EPS);
    float v = (h[i] - mu) * inv * gamma[f] + bnb[f] + xprev[i];
    h[i] = v > 0.f ? v : 0.f;
}

// out = x @ W1 + b1  [N,64]@[64,64]
__global__ __launch_bounds__(256) void final_kernel(const float* __restrict__ xcur,
        const float* __restrict__ W1, const float* __restrict__ b1,
        float* __restrict__ out, int n) {
    int wave = threadIdx.x >> 6, lane = threadIdx.x & 63;
    float w[HID];
#pragma unroll
    for (int k = 0; k < HID; ++k) w[k] = W1[k * OUT_F + lane];
    float bias = b1[lane];
    for (int base = blockIdx.x * 4; base < n; base += gridDim.x * 4) {
        int r = base + wave;
        if (r >= n) continue;           // wave-uniform
        float xv = xcur[r * HID + lane];
        float acc = bias;
#pragma unroll
        for (int k = 0; k < HID; ++k) acc += __shfl(xv, k, 64) * w[k];
        out[r * OUT_F + lane] = acc;
    }
}

extern "C" void kernel_launch(void* const* d_in, const int* in_sizes, int n_in,
                              void* d_out, int out_size, void* d_ws, size_t ws_size,
                              hipStream_t stream) {
    const float* x     = (const float*)d_in[0];
    const int*   edges = (const int*)d_in[1];
    const float* W0    = (const float*)d_in[2];
    const float* b0    = (const float*)d_in[3];
    const float* cw    = (const float*)d_in[4];
    const float* gamma = (const float*)d_in[5];
    const float* bnb   = (const float*)d_in[6];
    const float* W1    = (const float*)d_in[7];
    const float* b1    = (const float*)d_in[8];
    float* out = (float*)d_out;

    char* ws = (char*)d_ws;
    int*   cnt   = (int*)(ws + OFF_CNT);
    float* stats = (float*)(ws + OFF_STATS);
    float* dinv  = (float*)(ws + OFF_DINV);
    int*   rs    = (int*)(ws + OFF_ROWSTART);
    int*   cur   = (int*)(ws + OFF_CURSOR);
    int*   scol  = (int*)(ws + OFF_SORTED);
    float* x0    = (float*)(ws + OFF_X0);
    float* buf1  = (float*)(ws + OFF_BUF1);
    float* buf2  = (float*)(ws + OFF_BUF2);

    hipMemsetAsync(ws, 0, ZERO_BYTES, stream);
    hist_kernel<<<(N_EDGES + 255) / 256, 256, 0, stream>>>(edges, cnt, N_EDGES);
    dinv_kernel<<<(N_NODES + 255) / 256, 256, 0, stream>>>(cnt, dinv, N_NODES);
    scan_kernel<<<1, 1024, 0, stream>>>(cnt, rs, cur, N_NODES);
    scatter_kernel<<<(N_EDGES + 255) / 256, 256, 0, stream>>>(edges, cur, scol, N_EDGES);
    fc0_kernel<<<768, 256, 0, stream>>>(x, W0, b0, x0, N_NODES);

    const float* xc = x0;
    float* bufs[2] = { buf1, buf2 };
    for (int i = 0; i < NLAYERS; ++i) {
        float beta = logf(0.5f / (float)(i + 1) + 1.0f);
        float* hb = bufs[i & 1];
        layerA_kernel<<<1024, 256, 0, stream>>>(xc, x0, dinv, rs, scol,
                cw + (size_t)i * HID * HID, hb, stats + i * 128, beta, N_NODES);
        layerB_kernel<<<(N_NODES * HID + 255) / 256, 256, 0, stream>>>(hb, xc,
                stats + i * 128, gamma + i * HID, bnb + i * HID, N_NODES * HID);
        xc = hb;
    }
    final_kernel<<<1024, 256, 0, stream>>>(xc, W1, b1, out, N_NODES);
}